// Round 1
// 3597.988 us; speedup vs baseline: 1.2638x; 1.2638x over previous
//
#include <hip/hip_runtime.h>
#include <math.h>

#define B_ 64
#define T_ 512
#define F_ 128
#define H_ 512
#define NBLK 192
#define SPIN_MAX (1 << 23)

typedef short bf16x8 __attribute__((ext_vector_type(8)));
typedef float f32x4 __attribute__((ext_vector_type(4)));
typedef int   i32x4 __attribute__((ext_vector_type(4)));

// Round-to-nearest bf16.
__device__ __forceinline__ unsigned short bf_rn(float f) {
    unsigned u = __float_as_uint(f);
    u += 0x7FFF + ((u >> 16) & 1);
    return (unsigned short)(u >> 16);
}

// fp32 -> packed (lo_bf16 << 16) | hi_bf16 (hi RN, lo = RN(residual)).
__device__ __forceinline__ unsigned packsplit(float f) {
    const unsigned short hi = bf_rn(f);
    const float lof = f - __uint_as_float((unsigned)hi << 16);
    return ((unsigned)bf_rn(lof) << 16) | hi;
}

// ---------------------------------------------------------------------------
// One-time input transform: input[b][t][f] -> interleaved kpair stream
// xs[t][kpair=f>>1][b][{hiD,loD}]; hiD = hi(k even)|hi(k odd)<<16, loD same
// for lo-split. Write = coalesced u64 per (kpair,b).
// ---------------------------------------------------------------------------
__global__ void transpose_x(const float* __restrict__ in, unsigned* __restrict__ xs) {
    const int t = blockIdx.x;
    for (int idx = threadIdx.x; idx < B_ * F_ / 2; idx += blockDim.x) {
        const int kp = idx >> 6;        // 0..63
        const int bb = idx & 63;
        const float v0 = in[(size_t)bb * T_ * F_ + (size_t)t * F_ + 2 * kp];
        const float v1 = in[(size_t)bb * T_ * F_ + (size_t)t * F_ + 2 * kp + 1];
        const unsigned P0 = packsplit(v0), P1 = packsplit(v1);
        const unsigned hiD = __builtin_amdgcn_perm(P1, P0, 0x05040100u);
        const unsigned loD = __builtin_amdgcn_perm(P1, P0, 0x07060302u);
        unsigned* dst = xs + (size_t)t * 8192 + (size_t)kp * 128 + bb * 2;
        dst[0] = hiD; dst[1] = loD;
    }
}

__device__ __forceinline__ float sigmoid_(float x) { return 1.0f / (1.0f + expf(-x)); }

// Device-coherent ops (relaxed agent-scope atomics -> sc1 point-to-point).
__device__ __forceinline__ unsigned long long loadc_u64(const unsigned* p) {
    return __hip_atomic_load((const unsigned long long*)p, __ATOMIC_RELAXED,
                             __HIP_MEMORY_SCOPE_AGENT);
}
__device__ __forceinline__ void storec_u64(unsigned* p, unsigned long long v) {
    __hip_atomic_store((unsigned long long*)p, v, __ATOMIC_RELAXED,
                       __HIP_MEMORY_SCOPE_AGENT);
}
__device__ __forceinline__ void storec_f(float* p, float v) {
    __hip_atomic_store(p, v, __ATOMIC_RELAXED, __HIP_MEMORY_SCOPE_AGENT);
}
__device__ __forceinline__ float loadc_f(const float* p) {
    return __hip_atomic_load(p, __ATOMIC_RELAXED, __HIP_MEMORY_SCOPE_AGENT);
}

// ---------------------------------------------------------------------------
// Fence-free grid barrier with bounded spins (proven R6-R10).
// ---------------------------------------------------------------------------
__device__ __forceinline__ void gbar(int* __restrict__ slots, int* __restrict__ go,
                                     int bid, int tid, int e) {
    asm volatile("s_waitcnt vmcnt(0) lgkmcnt(0)" ::: "memory");
    __syncthreads();
    if (tid == 0)
        __hip_atomic_store(&slots[bid * 16], e, __ATOMIC_RELAXED,
                           __HIP_MEMORY_SCOPE_AGENT);
    if (bid == 0) {
        for (int s2 = tid; s2 < NBLK; s2 += 256) {
            int guard = 0;
            while (__hip_atomic_load(&slots[s2 * 16], __ATOMIC_RELAXED,
                                     __HIP_MEMORY_SCOPE_AGENT) < e &&
                   ++guard < SPIN_MAX)
                __builtin_amdgcn_s_sleep(1);
        }
        __syncthreads();
        if (tid == 0)
            __hip_atomic_store(go, e, __ATOMIC_RELAXED, __HIP_MEMORY_SCOPE_AGENT);
    } else if (tid == 0) {
        int guard = 0;
        while (__hip_atomic_load(go, __ATOMIC_RELAXED,
                                 __HIP_MEMORY_SCOPE_AGENT) < e &&
               ++guard < SPIN_MAX)
            __builtin_amdgcn_s_sleep(1);
    }
    __syncthreads();
}

// ---------------------------------------------------------------------------
// One step's GEMM: D[2 x 16 gate-rows][16 b] over K = [x-seg|h-seg].
// A = weights (split bf16) from LDS frag-order (conflict-free b128), TWO
// row-groups per kstep (32 gate-rows / block -> 64 blocks/layer halves the
// coherent h/x broadcast traffic vs 128 blocks/layer).
// B = interleaved kpair stream: lane (b=16w+n, oct=lane>>4) loads 4 u64 per
// kstep at dword (kstep*2048 + oct*512 + p2*128 + b*2) -> {hiD,loD} pairs.
// BH/BL fragments are register selection, ZERO pack VALU.
// 6 independent MFMA chains (hh, lh, hl x 2 row-groups). 8-deep pipeline.
// ---------------------------------------------------------------------------
template <int NKX, bool XCOH>
__device__ __forceinline__ void step_mfma(const unsigned* __restrict__ xs_l,
                                          const unsigned* __restrict__ hs_l,
                                          const unsigned short* wfrag,
                                          const int lane, f32x4 (&acc)[2][3]) {
    constexpr int NK = NKX + 16;      // total ksteps (K/32)
    unsigned long long v[8][4];       // [pipe][p2] = {hiD, loD}

    auto load4 = [&](unsigned long long* d, int i) {
        const unsigned* p = (i < NKX) ? (xs_l + (size_t)i * 2048)
                                      : (hs_l + (size_t)(i - NKX) * 2048);
        if ((i < NKX) ? XCOH : true) {
#pragma unroll
            for (int q = 0; q < 4; ++q) d[q] = loadc_u64(p + q * 128);
        } else {
#pragma unroll
            for (int q = 0; q < 4; ++q) d[q] = *(const unsigned long long*)(p + q * 128);
        }
    };

#pragma unroll
    for (int p = 0; p < 8; ++p) load4(v[p], p);

#pragma unroll
    for (int i = 0; i < NK; ++i) {
        union Frag { i32x4 i4; bf16x8 s; } BH, BL, AH0, AL0, AH1, AL1;
        const unsigned long long* d = v[i % 8];
#pragma unroll
        for (int p2 = 0; p2 < 4; ++p2) {
            BH.i4[p2] = (int)(unsigned)d[p2];          // hiD(kpair p2)
            BL.i4[p2] = (int)(unsigned)(d[p2] >> 32);  // loD(kpair p2)
        }
        if (i + 8 < NK) load4(v[i % 8], i + 8);
        AH0.i4 = *(const i32x4*)&wfrag[i * 2048 + lane * 8];
        AL0.i4 = *(const i32x4*)&wfrag[i * 2048 + 512 + lane * 8];
        AH1.i4 = *(const i32x4*)&wfrag[i * 2048 + 1024 + lane * 8];
        AL1.i4 = *(const i32x4*)&wfrag[i * 2048 + 1536 + lane * 8];
        acc[0][0] = __builtin_amdgcn_mfma_f32_16x16x32_bf16(AH0.s, BH.s, acc[0][0], 0, 0, 0);
        acc[0][1] = __builtin_amdgcn_mfma_f32_16x16x32_bf16(AL0.s, BH.s, acc[0][1], 0, 0, 0);
        acc[0][2] = __builtin_amdgcn_mfma_f32_16x16x32_bf16(AH0.s, BL.s, acc[0][2], 0, 0, 0);
        acc[1][0] = __builtin_amdgcn_mfma_f32_16x16x32_bf16(AH1.s, BH.s, acc[1][0], 0, 0, 0);
        acc[1][1] = __builtin_amdgcn_mfma_f32_16x16x32_bf16(AL1.s, BH.s, acc[1][1], 0, 0, 0);
        acc[1][2] = __builtin_amdgcn_mfma_f32_16x16x32_bf16(AH1.s, BL.s, acc[1][2], 0, 0, 0);
    }
}

// ---------------------------------------------------------------------------
// Persistent layer-pipelined LSTM scan. Block (layer=bid>>6, cb=bid&63) owns
// 32 gate-rows (cols c0..c0+7 x gates i,f,g,o); wave w owns b-tile
// [16w,16w+16). Lane (n,q) finalizes (b=16w+n, cols c0+q and c0+4+q)
// in-register; h written as interleaved kpair stream (next step's B layout):
// lane pairs cols via shfl_xor(16), even-q lanes store coherent u64 {hiD,loD}.
// 64 blocks/layer (vs 128) halves the LLC-served coherent broadcast traffic,
// which the R0 counters showed to be the bottleneck (~9 TB/s sc1 reads,
// MfmaUtil 10%, HBM 3%).
// ---------------------------------------------------------------------------
__global__ void __launch_bounds__(256, 1) lstm_scan(
    const unsigned* __restrict__ xs, unsigned* __restrict__ hb,
    float* __restrict__ h1s, float* __restrict__ out,
    int* __restrict__ bar_slots, int* __restrict__ bar_go,
    const float* __restrict__ Wih0, const float* __restrict__ Whh0,
    const float* __restrict__ bih0, const float* __restrict__ bhh0,
    const float* __restrict__ Wih1, const float* __restrict__ Whh1,
    const float* __restrict__ bih1, const float* __restrict__ bhh1,
    const float* __restrict__ Wih2, const float* __restrict__ Whh2,
    const float* __restrict__ bih2, const float* __restrict__ bhh2,
    const float* __restrict__ fcW1, const float* __restrict__ fcb1,
    const float* __restrict__ fcW2, const float* __restrict__ fcb2) {
    __shared__ unsigned short wfrag[64 * 1024];   // [kstep][rg0 hi|lo][rg1 hi|lo], 128 KB
    __shared__ float redsc[4 * 64];               // FC-head reduction only

    const float* WihA[3] = {Wih0, Wih1, Wih2};
    const float* WhhA[3] = {Whh0, Whh1, Whh2};
    const float* bihA[3] = {bih0, bih1, bih2};
    const float* bhhA[3] = {bhh0, bhh1, bhh2};

    const int tid   = threadIdx.x;
    const int bid   = blockIdx.x;
    const int layer = bid >> 6;
    const int cb    = bid & 63;
    const int c0    = cb * 8;
    const int lane  = tid & 63;
    const int w     = __builtin_amdgcn_readfirstlane(tid >> 6);
    const int KX    = (layer == 0) ? F_ : H_;
    const int NK    = KX / 32 + 16;

    const float* wih = WihA[layer];
    const float* whh = WhhA[layer];

    // ---- Stage weights once: split bf16 (RN both terms), A-frag order,
    // two row-groups (rg) per kstep.
    for (int idx = tid; idx < NK * 1024; idx += 256) {
        const int i = idx >> 10, rem = idx & 1023;
        const int rg = rem >> 9, r2 = rem & 511;
        const int l = r2 >> 3, j = r2 & 7;
        const int m = l & 15;
        const int grow = (m & 3) * 512 + c0 + rg * 4 + (m >> 2);
        const int k = i * 32 + (l >> 4) * 8 + j;
        const float f = (k < KX) ? wih[(size_t)grow * KX + k]
                                 : whh[(size_t)grow * 512 + (k - KX)];
        const unsigned short hi = bf_rn(f);
        const float lof = f - __uint_as_float((unsigned)hi << 16);
        wfrag[i * 2048 + rg * 1024 + l * 8 + j]       = hi;
        wfrag[i * 2048 + rg * 1024 + 512 + l * 8 + j] = bf_rn(lof);
    }
    __syncthreads();

    // Finalize-role constants: lane owns (b = 16w + n, cols c0+rg*4+q).
    const int fb    = w * 16 + (lane & 15);
    const int q     = lane >> 4;
    float bias[2][4];
#pragma unroll
    for (int rg = 0; rg < 2; ++rg)
#pragma unroll
        for (int g = 0; g < 4; ++g)
            bias[rg][g] = bihA[layer][g * 512 + c0 + rg * 4 + q] +
                          bhhA[layer][g * 512 + c0 + rg * 4 + q];

    // h buffers: [layer][parity][kpair 256][b 64][{hiD,loD}] dwords.
    unsigned* hb_l = hb + (size_t)layer * 65536;
    const unsigned* hb_in = hb + (size_t)(layer - 1) * 65536;
    // This lane-pair's store slots (even-q lanes store): kpair = col>>1.
    int hstore[2];
#pragma unroll
    for (int rg = 0; rg < 2; ++rg)
        hstore[rg] = ((c0 + rg * 4 + q) >> 1) * 128 + fb * 2;

    float c_reg[2] = {0.0f, 0.0f};
    const int laneoff = q * 512 + fb * 2;   // oct=q: consumer base offset (dwords)

    for (int s = 0; s < T_ + 2; ++s) {
        const int t = s - layer;
        if (t >= 0 && t < T_) {
            const int p_out  = t & 1;
            const int p_prev = (t + 1) & 1;
            const unsigned* xs_l =
                ((layer == 0) ? (xs + (size_t)t * 8192)
                              : (hb_in + (size_t)p_out * 32768)) + laneoff;
            const unsigned* hs_l = hb_l + (size_t)p_prev * 32768 + laneoff;

            f32x4 acc[2][3] = {{{0.f,0.f,0.f,0.f},{0.f,0.f,0.f,0.f},{0.f,0.f,0.f,0.f}},
                               {{0.f,0.f,0.f,0.f},{0.f,0.f,0.f,0.f},{0.f,0.f,0.f,0.f}}};
            if (layer == 0) step_mfma<4, false>(xs_l, hs_l, wfrag, lane, acc);
            else            step_mfma<16, true>(xs_l, hs_l, wfrag, lane, acc);

            // In-register finalize: reg g of acc[rg] = gate g of (fb, c0+rg*4+q).
#pragma unroll
            for (int rg = 0; rg < 2; ++rg) {
                float a[4];
#pragma unroll
                for (int g = 0; g < 4; ++g)
                    a[g] = bias[rg][g] + acc[rg][0][g] + acc[rg][1][g] + acc[rg][2][g];

                const float ig = sigmoid_(a[0]);
                const float fg = sigmoid_(a[1]);
                const float gg = tanhf(a[2]);
                const float og = sigmoid_(a[3]);
                c_reg[rg] = fg * c_reg[rg] + ig * gg;
                const float hv = og * tanhf(c_reg[rg]);

                // Pair columns (q, q^1) via shfl_xor(16); even-q lane stores u64.
                const unsigned P0 = packsplit(hv);
                const unsigned P1 = (unsigned)__shfl_xor((int)P0, 16, 64);
                if ((q & 1) == 0) {
                    const unsigned hiD = __builtin_amdgcn_perm(P1, P0, 0x05040100u);
                    const unsigned loD = __builtin_amdgcn_perm(P1, P0, 0x07060302u);
                    storec_u64(&hb_l[(size_t)p_out * 32768 + hstore[rg]],
                               ((unsigned long long)loD << 32) | hiD);
                }
            }
        }
        gbar(bar_slots, bar_go, bid, tid, s + 1);
    }

    // ---- FC head. h2 = layer-2 h at t=511 (parity 1), interleaved layout.
    const unsigned* h2u = hb + (size_t)2 * 65536 + 32768;
    const int fcb = tid & 63;
    if (bid < 64) {
        float part = 0.0f;
        const float* wrow = fcW1 + (size_t)bid * H_ + w * 128;
#pragma unroll 8
        for (int k = 0; k < 128; ++k) {
            const int kk = w * 128 + k;
            const unsigned long long d =
                loadc_u64(h2u + (kk >> 1) * 128 + fcb * 2);
            const unsigned hiD = (unsigned)d, loD = (unsigned)(d >> 32);
            const int sh = (kk & 1) * 16;
            const float val =
                __uint_as_float(((hiD >> sh) & 0xFFFFu) << 16) +
                __uint_as_float(((loD >> sh) & 0xFFFFu) << 16);
            part = fmaf(wrow[k], val, part);
        }
        redsc[w * 64 + fcb] = part;
        __syncthreads();
        if (tid < 64) {
            float acc2 = fcb1[bid] + redsc[tid] + redsc[64 + tid] +
                         redsc[128 + tid] + redsc[192 + tid];
            storec_f(&h1s[bid * B_ + tid], fmaxf(acc2, 0.0f));
        }
    }
    gbar(bar_slots, bar_go, bid, tid, T_ + 3);
    if (bid == 0 && tid < 64) {
        float acc2 = fcb2[0];
#pragma unroll
        for (int c = 0; c < 64; ++c)
            acc2 = fmaf(fcW2[c], loadc_f(&h1s[c * B_ + tid]), acc2);
        out[tid] = fmaxf(acc2, 0.0f);
    }
}

// ---------------------------------------------------------------------------
extern "C" void kernel_launch(void* const* d_in, const int* in_sizes, int n_in,
                              void* d_out, int out_size, void* d_ws, size_t ws_size,
                              hipStream_t stream) {
    const float* in    = (const float*)d_in[0];
    const float* Wih0  = (const float*)d_in[1];
    const float* Whh0  = (const float*)d_in[2];
    const float* bih0  = (const float*)d_in[3];
    const float* bhh0  = (const float*)d_in[4];
    const float* Wih1  = (const float*)d_in[5];
    const float* Whh1  = (const float*)d_in[6];
    const float* bih1  = (const float*)d_in[7];
    const float* bhh1  = (const float*)d_in[8];
    const float* Wih2  = (const float*)d_in[9];
    const float* Whh2  = (const float*)d_in[10];
    const float* bih2  = (const float*)d_in[11];
    const float* bhh2  = (const float*)d_in[12];
    const float* fcW1  = (const float*)d_in[13];
    const float* fcb1  = (const float*)d_in[14];
    const float* fcW2  = (const float*)d_in[15];
    const float* fcb2  = (const float*)d_in[16];
    float* outp = (float*)d_out;

    unsigned* xs  = (unsigned*)d_ws;                   // [T][8192]       16 MB
    unsigned* hbf = xs + (size_t)T_ * 8192;            // [3][2][32768]  768 KB
    float*    h1s = (float*)(hbf + (size_t)3 * 65536); // [64][64]        16 KB
    int*      bar = (int*)(h1s + 64 * 64);
    int*      bar_slots = bar;                         // NBLK*16 ints
    int*      bar_go    = bar + NBLK * 16;             // 1 int

    hipMemsetAsync(hbf, 0,
                   ((size_t)3 * 65536 + 64 * 64 + NBLK * 16 + 16) * sizeof(int),
                   stream);

    transpose_x<<<dim3(T_), dim3(256), 0, stream>>>(in, xs);

    void* args[] = {
        (void*)&xs, (void*)&hbf, (void*)&h1s, (void*)&outp,
        (void*)&bar_slots, (void*)&bar_go,
        (void*)&Wih0, (void*)&Whh0, (void*)&bih0, (void*)&bhh0,
        (void*)&Wih1, (void*)&Whh1, (void*)&bih1, (void*)&bhh1,
        (void*)&Wih2, (void*)&Whh2, (void*)&bih2, (void*)&bhh2,
        (void*)&fcW1, (void*)&fcb1, (void*)&fcW2, (void*)&fcb2};
    hipLaunchCooperativeKernel((void*)lstm_scan, dim3(NBLK), dim3(256), args, 0, stream);
}

// Round 2
// 3227.766 us; speedup vs baseline: 1.4088x; 1.1147x over previous
//
#include <hip/hip_runtime.h>
#include <hip/hip_fp16.h>
#include <math.h>

#define B_ 64
#define T_ 512
#define F_ 128
#define H_ 512
#define NBLK 96
#define SPIN_MAX (1 << 23)

typedef _Float16 f16x8 __attribute__((ext_vector_type(8)));
typedef float f32x4 __attribute__((ext_vector_type(4)));
typedef int   i32x4 __attribute__((ext_vector_type(4)));

__device__ __forceinline__ unsigned short f2h(float f) {
    return __half_as_ushort(__float2half(f));   // RN
}
__device__ __forceinline__ float h2f(unsigned short u) {
    return __half2float(__ushort_as_half(u));
}

// ---------------------------------------------------------------------------
// One-time input transform: input[b][t][f] -> fp16 kquad stream
// xs[t][kp2=f>>2][b][{dw0,dw1}]; dw_p = fp16(4kp2+2p) | fp16(4kp2+2p+1)<<16.
// Flat layout = [kp2_global][b][dw] dwords; consumer kstep j = kp2 j*8..j*8+7.
// ---------------------------------------------------------------------------
__global__ void transpose_x(const float* __restrict__ in, unsigned* __restrict__ xs) {
    const int t = blockIdx.x;
    for (int idx = threadIdx.x; idx < B_ * F_ / 4; idx += blockDim.x) {
        const int kp2 = idx >> 6;       // 0..31
        const int bb = idx & 63;
        const float* src = in + (size_t)bb * T_ * F_ + (size_t)t * F_ + 4 * kp2;
        const unsigned h0 = f2h(src[0]), h1 = f2h(src[1]);
        const unsigned h2 = f2h(src[2]), h3 = f2h(src[3]);
        const unsigned dw0 = h0 | (h1 << 16);
        const unsigned dw1 = h2 | (h3 << 16);
        *(unsigned long long*)(xs + (size_t)t * 4096 + (size_t)kp2 * 128 + bb * 2) =
            ((unsigned long long)dw1 << 32) | dw0;
    }
}

__device__ __forceinline__ float sigmoid_(float x) { return 1.0f / (1.0f + expf(-x)); }

// Device-coherent ops (relaxed agent-scope atomics -> sc1 point-to-point).
__device__ __forceinline__ unsigned long long loadc_u64(const unsigned* p) {
    return __hip_atomic_load((const unsigned long long*)p, __ATOMIC_RELAXED,
                             __HIP_MEMORY_SCOPE_AGENT);
}
__device__ __forceinline__ unsigned loadc_u32(const unsigned* p) {
    return __hip_atomic_load(p, __ATOMIC_RELAXED, __HIP_MEMORY_SCOPE_AGENT);
}
__device__ __forceinline__ void storec_u64(unsigned* p, unsigned long long v) {
    __hip_atomic_store((unsigned long long*)p, v, __ATOMIC_RELAXED,
                       __HIP_MEMORY_SCOPE_AGENT);
}
__device__ __forceinline__ void storec_f(float* p, float v) {
    __hip_atomic_store(p, v, __ATOMIC_RELAXED, __HIP_MEMORY_SCOPE_AGENT);
}
__device__ __forceinline__ float loadc_f(const float* p) {
    return __hip_atomic_load(p, __ATOMIC_RELAXED, __HIP_MEMORY_SCOPE_AGENT);
}

// ---------------------------------------------------------------------------
// Fence-free grid barrier with bounded spins (proven R6-R10).
// ---------------------------------------------------------------------------
__device__ __forceinline__ void gbar(int* __restrict__ slots, int* __restrict__ go,
                                     int bid, int tid, int e) {
    asm volatile("s_waitcnt vmcnt(0) lgkmcnt(0)" ::: "memory");
    __syncthreads();
    if (tid == 0)
        __hip_atomic_store(&slots[bid * 16], e, __ATOMIC_RELAXED,
                           __HIP_MEMORY_SCOPE_AGENT);
    if (bid == 0) {
        for (int s2 = tid; s2 < NBLK; s2 += 256) {
            int guard = 0;
            while (__hip_atomic_load(&slots[s2 * 16], __ATOMIC_RELAXED,
                                     __HIP_MEMORY_SCOPE_AGENT) < e &&
                   ++guard < SPIN_MAX)
                __builtin_amdgcn_s_sleep(1);
        }
        __syncthreads();
        if (tid == 0)
            __hip_atomic_store(go, e, __ATOMIC_RELAXED, __HIP_MEMORY_SCOPE_AGENT);
    } else if (tid == 0) {
        int guard = 0;
        while (__hip_atomic_load(go, __ATOMIC_RELAXED,
                                 __HIP_MEMORY_SCOPE_AGENT) < e &&
               ++guard < SPIN_MAX)
            __builtin_amdgcn_s_sleep(1);
    }
    __syncthreads();
}

// ---------------------------------------------------------------------------
// One step's GEMM: D[4 x 16 gate-rows][16 b] over K = [x-seg|h-seg].
// Single fp16 everywhere (no residual split): 1 MFMA chain per row-group,
// 64 gate-rows per block -> 32 blocks/layer -> coherent broadcast traffic
// 10 MB/epoch (was 40 with split-bf16 / 32-row blocks).
// B = fp16 kquad stream: lane (b=16w+n, oct=lane>>4) loads 2 u64 per kstep at
// dword (kstep*1024 + oct*256 + pp*128 + b*2); frag = register selection.
// 4 independent MFMA chains. 8-deep load pipeline.
// ---------------------------------------------------------------------------
template <int NKX, bool XCOH>
__device__ __forceinline__ void step_mfma(const unsigned* __restrict__ xs_l,
                                          const unsigned* __restrict__ hs_l,
                                          const unsigned short* wfrag,
                                          const int lane, f32x4 (&acc)[4]) {
    constexpr int NK = NKX + 16;      // total ksteps (K/32)
    unsigned long long v[8][2];       // [pipe][pp]

    auto load2 = [&](unsigned long long* d, int i) {
        const unsigned* p = (i < NKX) ? (xs_l + (size_t)i * 1024)
                                      : (hs_l + (size_t)(i - NKX) * 1024);
        if ((i < NKX) ? XCOH : true) {
            d[0] = loadc_u64(p);
            d[1] = loadc_u64(p + 128);
        } else {
            d[0] = *(const unsigned long long*)p;
            d[1] = *(const unsigned long long*)(p + 128);
        }
    };

#pragma unroll
    for (int p = 0; p < 8; ++p) load2(v[p], p);

#pragma unroll
    for (int i = 0; i < NK; ++i) {
        union Frag { i32x4 i4; f16x8 s; } Bf, A0, A1, A2, A3;
        const unsigned long long* d = v[i % 8];
        Bf.i4[0] = (int)(unsigned)d[0];
        Bf.i4[1] = (int)(unsigned)(d[0] >> 32);
        Bf.i4[2] = (int)(unsigned)d[1];
        Bf.i4[3] = (int)(unsigned)(d[1] >> 32);
        if (i + 8 < NK) load2(v[i % 8], i + 8);
        A0.i4 = *(const i32x4*)&wfrag[i * 2048 + lane * 8];
        A1.i4 = *(const i32x4*)&wfrag[i * 2048 + 512 + lane * 8];
        A2.i4 = *(const i32x4*)&wfrag[i * 2048 + 1024 + lane * 8];
        A3.i4 = *(const i32x4*)&wfrag[i * 2048 + 1536 + lane * 8];
        acc[0] = __builtin_amdgcn_mfma_f32_16x16x32_f16(A0.s, Bf.s, acc[0], 0, 0, 0);
        acc[1] = __builtin_amdgcn_mfma_f32_16x16x32_f16(A1.s, Bf.s, acc[1], 0, 0, 0);
        acc[2] = __builtin_amdgcn_mfma_f32_16x16x32_f16(A2.s, Bf.s, acc[2], 0, 0, 0);
        acc[3] = __builtin_amdgcn_mfma_f32_16x16x32_f16(A3.s, Bf.s, acc[3], 0, 0, 0);
    }
}

// ---------------------------------------------------------------------------
// Persistent layer-pipelined LSTM scan. Block (layer=bid>>5, cb=bid&31) owns
// 64 gate-rows (cols c0..c0+15 x gates i,f,g,o); wave w owns b-tile
// [16w,16w+16). Lane (n,q) finalizes (b=16w+n, cols c0+rg*4+q, rg=0..3)
// in-register; h written as fp16 kquad stream (next step's B layout):
// cols pair via shfl_xor(16) into dwords, dwords pair via shfl_xor(32) into
// u64; q==0 lanes store coherent u64.
// ---------------------------------------------------------------------------
__global__ void __launch_bounds__(256, 1) lstm_scan(
    const unsigned* __restrict__ xs, unsigned* __restrict__ hb,
    float* __restrict__ h1s, float* __restrict__ out,
    int* __restrict__ bar_slots, int* __restrict__ bar_go,
    const float* __restrict__ Wih0, const float* __restrict__ Whh0,
    const float* __restrict__ bih0, const float* __restrict__ bhh0,
    const float* __restrict__ Wih1, const float* __restrict__ Whh1,
    const float* __restrict__ bih1, const float* __restrict__ bhh1,
    const float* __restrict__ Wih2, const float* __restrict__ Whh2,
    const float* __restrict__ bih2, const float* __restrict__ bhh2,
    const float* __restrict__ fcW1, const float* __restrict__ fcb1,
    const float* __restrict__ fcW2, const float* __restrict__ fcb2) {
    __shared__ unsigned short wfrag[32 * 2048];   // [kstep][rg 4][512], 128 KB
    __shared__ float redsc[4 * 64];               // FC-head reduction only

    const float* WihA[3] = {Wih0, Wih1, Wih2};
    const float* WhhA[3] = {Whh0, Whh1, Whh2};
    const float* bihA[3] = {bih0, bih1, bih2};
    const float* bhhA[3] = {bhh0, bhh1, bhh2};

    const int tid   = threadIdx.x;
    const int bid   = blockIdx.x;
    const int layer = bid >> 5;
    const int cb    = bid & 31;
    const int c0    = cb * 16;
    const int lane  = tid & 63;
    const int w     = __builtin_amdgcn_readfirstlane(tid >> 6);
    const int KX    = (layer == 0) ? F_ : H_;
    const int NK    = KX / 32 + 16;

    const float* wih = WihA[layer];
    const float* whh = WhhA[layer];

    // ---- Stage weights once: fp16 RN, A-frag order, 4 row-groups per kstep.
    for (int idx = tid; idx < NK * 2048; idx += 256) {
        const int i = idx >> 11, rem = idx & 2047;
        const int rg = rem >> 9, r2 = rem & 511;
        const int l = r2 >> 3, j = r2 & 7;
        const int m = l & 15;
        const int grow = (m & 3) * 512 + c0 + rg * 4 + (m >> 2);
        const int k = i * 32 + (l >> 4) * 8 + j;
        const float f = (k < KX) ? wih[(size_t)grow * KX + k]
                                 : whh[(size_t)grow * 512 + (k - KX)];
        wfrag[i * 2048 + rg * 512 + l * 8 + j] = f2h(f);
    }
    __syncthreads();

    // Finalize-role constants: lane owns (b = 16w + n, cols c0+rg*4+q).
    const int fb    = w * 16 + (lane & 15);
    const int q     = lane >> 4;
    float bias[4][4];
#pragma unroll
    for (int rg = 0; rg < 4; ++rg)
#pragma unroll
        for (int g = 0; g < 4; ++g)
            bias[rg][g] = bihA[layer][g * 512 + c0 + rg * 4 + q] +
                          bhhA[layer][g * 512 + c0 + rg * 4 + q];

    // h buffers: [layer][parity][kp2 128][b 64][2 dw] dwords (fp16 stream).
    unsigned* hb_l = hb + (size_t)layer * 32768;
    const unsigned* hb_in = hb + (size_t)(layer - 1) * 32768;
    // This lane-quad's store slots (q==0 lanes store): kp2 = (c0+rg*4)>>2.
    int hstore[4];
#pragma unroll
    for (int rg = 0; rg < 4; ++rg)
        hstore[rg] = (cb * 4 + rg) * 128 + fb * 2;

    float c_reg[4] = {0.0f, 0.0f, 0.0f, 0.0f};
    const int laneoff = q * 256 + fb * 2;   // oct=q: consumer base offset (dwords)

    for (int s = 0; s < T_ + 2; ++s) {
        const int t = s - layer;
        if (t >= 0 && t < T_) {
            const int p_out  = t & 1;
            const int p_prev = (t + 1) & 1;
            const unsigned* xs_l =
                ((layer == 0) ? (xs + (size_t)t * 4096)
                              : (hb_in + (size_t)p_out * 16384)) + laneoff;
            const unsigned* hs_l = hb_l + (size_t)p_prev * 16384 + laneoff;

            f32x4 acc[4] = {{0.f,0.f,0.f,0.f},{0.f,0.f,0.f,0.f},
                            {0.f,0.f,0.f,0.f},{0.f,0.f,0.f,0.f}};
            if (layer == 0) step_mfma<4, false>(xs_l, hs_l, wfrag, lane, acc);
            else            step_mfma<16, true>(xs_l, hs_l, wfrag, lane, acc);

            // In-register finalize: reg g of acc[rg] = gate g of (fb, c0+rg*4+q).
#pragma unroll
            for (int rg = 0; rg < 4; ++rg) {
                float a[4];
#pragma unroll
                for (int g = 0; g < 4; ++g)
                    a[g] = bias[rg][g] + acc[rg][g];

                const float ig = sigmoid_(a[0]);
                const float fg = sigmoid_(a[1]);
                const float gg = tanhf(a[2]);
                const float og = sigmoid_(a[3]);
                c_reg[rg] = fg * c_reg[rg] + ig * gg;
                const float hv = og * tanhf(c_reg[rg]);

                // cols (q,q^1) pair via shfl_xor(16) -> dword; dwords (q=0,q=2)
                // pair via shfl_xor(32) -> u64; q==0 lane stores.
                const unsigned P0 = (unsigned)f2h(hv);
                const unsigned P1 = (unsigned)__shfl_xor((int)P0, 16, 64) & 0xFFFFu;
                const unsigned D  = P0 | (P1 << 16);
                const unsigned D2 = (unsigned)__shfl_xor((int)D, 32, 64);
                if (q == 0) {
                    storec_u64(&hb_l[(size_t)p_out * 16384 + hstore[rg]],
                               ((unsigned long long)D2 << 32) | D);
                }
            }
        }
        gbar(bar_slots, bar_go, bid, tid, s + 1);
    }

    // ---- FC head. h2 = layer-2 h at t=511 (parity 1), fp16 kquad layout.
    const unsigned* h2u = hb + (size_t)2 * 32768 + 16384;
    const int fcb = tid & 63;
    if (bid < 64) {
        float part = 0.0f;
        const float* wrow = fcW1 + (size_t)bid * H_ + w * 128;
#pragma unroll 8
        for (int k = 0; k < 128; ++k) {
            const int kk = w * 128 + k;
            const unsigned dv =
                loadc_u32(h2u + (kk >> 2) * 128 + fcb * 2 + ((kk >> 1) & 1));
            const float val = h2f((unsigned short)((dv >> ((kk & 1) * 16)) & 0xFFFFu));
            part = fmaf(wrow[k], val, part);
        }
        redsc[w * 64 + fcb] = part;
        __syncthreads();
        if (tid < 64) {
            float acc2 = fcb1[bid] + redsc[tid] + redsc[64 + tid] +
                         redsc[128 + tid] + redsc[192 + tid];
            storec_f(&h1s[bid * B_ + tid], fmaxf(acc2, 0.0f));
        }
    }
    gbar(bar_slots, bar_go, bid, tid, T_ + 3);
    if (bid == 0 && tid < 64) {
        float acc2 = fcb2[0];
#pragma unroll
        for (int c = 0; c < 64; ++c)
            acc2 = fmaf(fcW2[c], loadc_f(&h1s[c * B_ + tid]), acc2);
        out[tid] = fmaxf(acc2, 0.0f);
    }
}

// ---------------------------------------------------------------------------
extern "C" void kernel_launch(void* const* d_in, const int* in_sizes, int n_in,
                              void* d_out, int out_size, void* d_ws, size_t ws_size,
                              hipStream_t stream) {
    const float* in    = (const float*)d_in[0];
    const float* Wih0  = (const float*)d_in[1];
    const float* Whh0  = (const float*)d_in[2];
    const float* bih0  = (const float*)d_in[3];
    const float* bhh0  = (const float*)d_in[4];
    const float* Wih1  = (const float*)d_in[5];
    const float* Whh1  = (const float*)d_in[6];
    const float* bih1  = (const float*)d_in[7];
    const float* bhh1  = (const float*)d_in[8];
    const float* Wih2  = (const float*)d_in[9];
    const float* Whh2  = (const float*)d_in[10];
    const float* bih2  = (const float*)d_in[11];
    const float* bhh2  = (const float*)d_in[12];
    const float* fcW1  = (const float*)d_in[13];
    const float* fcb1  = (const float*)d_in[14];
    const float* fcW2  = (const float*)d_in[15];
    const float* fcb2  = (const float*)d_in[16];
    float* outp = (float*)d_out;

    unsigned* xs  = (unsigned*)d_ws;                   // [T][4096] dwords  8 MB
    unsigned* hbf = xs + (size_t)T_ * 4096;            // [3][2][16384]   384 KB
    float*    h1s = (float*)(hbf + (size_t)3 * 32768); // [64][64]         16 KB
    int*      bar = (int*)(h1s + 64 * 64);
    int*      bar_slots = bar;                         // NBLK*16 ints
    int*      bar_go    = bar + NBLK * 16;             // 1 int

    hipMemsetAsync(hbf, 0,
                   ((size_t)3 * 32768 + 64 * 64 + NBLK * 16 + 16) * sizeof(int),
                   stream);

    transpose_x<<<dim3(T_), dim3(256), 0, stream>>>(in, xs);

    void* args[] = {
        (void*)&xs, (void*)&hbf, (void*)&h1s, (void*)&outp,
        (void*)&bar_slots, (void*)&bar_go,
        (void*)&Wih0, (void*)&Whh0, (void*)&bih0, (void*)&bhh0,
        (void*)&Wih1, (void*)&Whh1, (void*)&bih1, (void*)&bhh1,
        (void*)&Wih2, (void*)&Whh2, (void*)&bih2, (void*)&bhh2,
        (void*)&fcW1, (void*)&fcb1, (void*)&fcW2, (void*)&fcb2};
    hipLaunchCooperativeKernel((void*)lstm_scan, dim3(NBLK), dim3(256), args, 0, stream);
}

// Round 4
// 2619.927 us; speedup vs baseline: 1.7356x; 1.2320x over previous
//
#include <hip/hip_runtime.h>
#include <hip/hip_fp16.h>
#include <math.h>

#define B_ 64
#define T_ 512
#define F_ 128
#define H_ 512
#define NBLK 96
#define SPIN_MAX (1 << 23)

typedef _Float16 f16x8 __attribute__((ext_vector_type(8)));
typedef float f32x4 __attribute__((ext_vector_type(4)));
typedef int   i32x4 __attribute__((ext_vector_type(4)));

__device__ __forceinline__ unsigned short f2h(float f) {
    return __half_as_ushort(__float2half(f));   // RN
}
__device__ __forceinline__ float h2f(unsigned short u) {
    return __half2float(__ushort_as_half(u));
}

// ---------------------------------------------------------------------------
// One-time input transform: input[b][t][f] -> fp16 kquad stream
// xs[t][kp2=f>>2][b][{dw0,dw1}]; dw_p = fp16(4kp2+2p) | fp16(4kp2+2p+1)<<16.
// ---------------------------------------------------------------------------
__global__ void transpose_x(const float* __restrict__ in, unsigned* __restrict__ xs) {
    const int t = blockIdx.x;
    for (int idx = threadIdx.x; idx < B_ * F_ / 4; idx += blockDim.x) {
        const int kp2 = idx >> 6;       // 0..31
        const int bb = idx & 63;
        const float* src = in + (size_t)bb * T_ * F_ + (size_t)t * F_ + 4 * kp2;
        const unsigned h0 = f2h(src[0]), h1 = f2h(src[1]);
        const unsigned h2 = f2h(src[2]), h3 = f2h(src[3]);
        const unsigned dw0 = h0 | (h1 << 16);
        const unsigned dw1 = h2 | (h3 << 16);
        *(unsigned long long*)(xs + (size_t)t * 4096 + (size_t)kp2 * 128 + bb * 2) =
            ((unsigned long long)dw1 << 32) | dw0;
    }
}

// Fast device transcendentals (v_exp_f32 + v_rcp_f32, ~1e-7 rel err; fp16
// datapath quantization dominates).
__device__ __forceinline__ float sigmoid_(float x) {
    return __builtin_amdgcn_rcpf(1.0f + __expf(-x));
}
__device__ __forceinline__ float tanh_(float x) {
    return 1.0f - 2.0f * __builtin_amdgcn_rcpf(1.0f + __expf(2.0f * x));
}

// Device-coherent ops (relaxed agent-scope atomics -> sc0/sc1 point-to-point).
__device__ __forceinline__ unsigned long long loadc_u64(const unsigned* p) {
    return __hip_atomic_load((const unsigned long long*)p, __ATOMIC_RELAXED,
                             __HIP_MEMORY_SCOPE_AGENT);
}
__device__ __forceinline__ unsigned loadc_u32(const unsigned* p) {
    return __hip_atomic_load(p, __ATOMIC_RELAXED, __HIP_MEMORY_SCOPE_AGENT);
}
__device__ __forceinline__ void storec_u64(unsigned* p, unsigned long long v) {
    __hip_atomic_store((unsigned long long*)p, v, __ATOMIC_RELAXED,
                       __HIP_MEMORY_SCOPE_AGENT);
}
__device__ __forceinline__ void storec_f(float* p, float v) {
    __hip_atomic_store(p, v, __ATOMIC_RELAXED, __HIP_MEMORY_SCOPE_AGENT);
}
__device__ __forceinline__ float loadc_f(const float* p) {
    return __hip_atomic_load(p, __ATOMIC_RELAXED, __HIP_MEMORY_SCOPE_AGENT);
}

// ---------------------------------------------------------------------------
// Flat all-to-all grid barrier: each block publishes its slot, then 96
// threads each poll one slot. ONE store->visibility->poll round trip (the
// old two-hop gather@block0 + go-broadcast cost two). Bounded spins ensure
// forward progress; slot values are monotonic so cross-epoch overlap is safe.
// ---------------------------------------------------------------------------
__device__ __forceinline__ void gbar(int* __restrict__ slots, int bid, int tid, int e) {
    asm volatile("s_waitcnt vmcnt(0) lgkmcnt(0)" ::: "memory");
    __syncthreads();
    if (tid == 0)
        __hip_atomic_store(&slots[bid * 16], e, __ATOMIC_RELAXED,
                           __HIP_MEMORY_SCOPE_AGENT);
    if (tid < NBLK) {
        int guard = 0;
        while (__hip_atomic_load(&slots[tid * 16], __ATOMIC_RELAXED,
                                 __HIP_MEMORY_SCOPE_AGENT) < e &&
               ++guard < SPIN_MAX)
            __builtin_amdgcn_s_sleep(1);
    }
    __syncthreads();
}

// ---------------------------------------------------------------------------
// One step's GEMM: D[4 x 16 gate-rows][16 b] over K = [x-seg|h-seg].
// Single fp16, 64 gate-rows/block, 32 blocks/layer.
// B = fp16 kquad stream; lane (b=16w+n, oct=lane>>4) loads 2 u64 per kstep.
// PD=16 pipeline: 32 loads (256 B/lane) in flight to cover ~900cy sc1
// latency (8-deep left the stream latency-bound at ~1.6 TB/s).
// ---------------------------------------------------------------------------
template <int NKX, bool XCOH>
__device__ __forceinline__ void step_mfma(const unsigned* __restrict__ xs_l,
                                          const unsigned* __restrict__ hs_l,
                                          const unsigned short* wfrag,
                                          const int lane, f32x4 (&acc)[4]) {
    constexpr int NK = NKX + 16;      // total ksteps (K/32)
    constexpr int PD = 16;            // pipeline depth
    unsigned long long v[PD][2];      // [pipe][pp]

    auto load2 = [&](unsigned long long* d, int i) {
        const unsigned* p = (i < NKX) ? (xs_l + (size_t)i * 1024)
                                      : (hs_l + (size_t)(i - NKX) * 1024);
        if ((i < NKX) ? XCOH : true) {
            d[0] = loadc_u64(p);
            d[1] = loadc_u64(p + 128);
        } else {
            d[0] = *(const unsigned long long*)p;
            d[1] = *(const unsigned long long*)(p + 128);
        }
    };

#pragma unroll
    for (int p = 0; p < PD; ++p) load2(v[p], p);

#pragma unroll
    for (int i = 0; i < NK; ++i) {
        union Frag { i32x4 i4; f16x8 s; } Bf, A0, A1, A2, A3;
        const unsigned long long* d = v[i % PD];
        Bf.i4[0] = (int)(unsigned)d[0];
        Bf.i4[1] = (int)(unsigned)(d[0] >> 32);
        Bf.i4[2] = (int)(unsigned)d[1];
        Bf.i4[3] = (int)(unsigned)(d[1] >> 32);
        if (i + PD < NK) load2(v[i % PD], i + PD);
        A0.i4 = *(const i32x4*)&wfrag[i * 2048 + lane * 8];
        A1.i4 = *(const i32x4*)&wfrag[i * 2048 + 512 + lane * 8];
        A2.i4 = *(const i32x4*)&wfrag[i * 2048 + 1024 + lane * 8];
        A3.i4 = *(const i32x4*)&wfrag[i * 2048 + 1536 + lane * 8];
        acc[0] = __builtin_amdgcn_mfma_f32_16x16x32_f16(A0.s, Bf.s, acc[0], 0, 0, 0);
        acc[1] = __builtin_amdgcn_mfma_f32_16x16x32_f16(A1.s, Bf.s, acc[1], 0, 0, 0);
        acc[2] = __builtin_amdgcn_mfma_f32_16x16x32_f16(A2.s, Bf.s, acc[2], 0, 0, 0);
        acc[3] = __builtin_amdgcn_mfma_f32_16x16x32_f16(A3.s, Bf.s, acc[3], 0, 0, 0);
    }
}

// ---------------------------------------------------------------------------
// Persistent layer-pipelined LSTM scan. Block (layer=bid>>5, cb=bid&31) owns
// 64 gate-rows (cols c0..c0+15 x gates i,f,g,o); wave w owns b-tile
// [16w,16w+16). Lane (n,q) finalizes (b=16w+n, cols c0+rg*4+q, rg=0..3)
// in-register; h written as fp16 kquad stream (next step's B layout).
// ---------------------------------------------------------------------------
__global__ void __launch_bounds__(256, 1) lstm_scan(
    const unsigned* __restrict__ xs, unsigned* __restrict__ hb,
    float* __restrict__ h1s, float* __restrict__ out,
    int* __restrict__ bar_slots, int* __restrict__ bar_go,
    const float* __restrict__ Wih0, const float* __restrict__ Whh0,
    const float* __restrict__ bih0, const float* __restrict__ bhh0,
    const float* __restrict__ Wih1, const float* __restrict__ Whh1,
    const float* __restrict__ bih1, const float* __restrict__ bhh1,
    const float* __restrict__ Wih2, const float* __restrict__ Whh2,
    const float* __restrict__ bih2, const float* __restrict__ bhh2,
    const float* __restrict__ fcW1, const float* __restrict__ fcb1,
    const float* __restrict__ fcW2, const float* __restrict__ fcb2) {
    __shared__ unsigned short wfrag[32 * 2048];   // [kstep][rg 4][512], 128 KB
    __shared__ float redsc[4 * 64];               // FC-head reduction only

    const float* WihA[3] = {Wih0, Wih1, Wih2};
    const float* WhhA[3] = {Whh0, Whh1, Whh2};
    const float* bihA[3] = {bih0, bih1, bih2};
    const float* bhhA[3] = {bhh0, bhh1, bhh2};

    const int tid   = threadIdx.x;
    const int bid   = blockIdx.x;
    const int layer = bid >> 5;
    const int cb    = bid & 31;
    const int c0    = cb * 16;
    const int lane  = tid & 63;
    const int w     = __builtin_amdgcn_readfirstlane(tid >> 6);
    const int KX    = (layer == 0) ? F_ : H_;
    const int NK    = KX / 32 + 16;

    const float* wih = WihA[layer];
    const float* whh = WhhA[layer];

    // ---- Stage weights once: fp16 RN, A-frag order, 4 row-groups per kstep.
    for (int idx = tid; idx < NK * 2048; idx += 256) {
        const int i = idx >> 11, rem = idx & 2047;
        const int rg = rem >> 9, r2 = rem & 511;
        const int l = r2 >> 3, j = r2 & 7;
        const int m = l & 15;
        const int grow = (m & 3) * 512 + c0 + rg * 4 + (m >> 2);
        const int k = i * 32 + (l >> 4) * 8 + j;
        const float f = (k < KX) ? wih[(size_t)grow * KX + k]
                                 : whh[(size_t)grow * 512 + (k - KX)];
        wfrag[i * 2048 + rg * 512 + l * 8 + j] = f2h(f);
    }
    __syncthreads();

    // Finalize-role constants: lane owns (b = 16w + n, cols c0+rg*4+q).
    const int fb    = w * 16 + (lane & 15);
    const int q     = lane >> 4;
    float bias[4][4];
#pragma unroll
    for (int rg = 0; rg < 4; ++rg)
#pragma unroll
        for (int g = 0; g < 4; ++g)
            bias[rg][g] = bihA[layer][g * 512 + c0 + rg * 4 + q] +
                          bhhA[layer][g * 512 + c0 + rg * 4 + q];

    // h buffers: [layer][parity][kp2 128][b 64][2 dw] dwords (fp16 stream).
    unsigned* hb_l = hb + (size_t)layer * 32768;
    const unsigned* hb_in = hb + (size_t)(layer - 1) * 32768;
    // This lane-quad's store slots (q==0 lanes store): kp2 = (c0+rg*4)>>2.
    int hstore[4];
#pragma unroll
    for (int rg = 0; rg < 4; ++rg)
        hstore[rg] = (cb * 4 + rg) * 128 + fb * 2;

    float c_reg[4] = {0.0f, 0.0f, 0.0f, 0.0f};
    const int laneoff = q * 256 + fb * 2;   // oct=q: consumer base offset (dwords)

    for (int s = 0; s < T_ + 2; ++s) {
        const int t = s - layer;
        if (t >= 0 && t < T_) {
            const int p_out  = t & 1;
            const int p_prev = (t + 1) & 1;
            const unsigned* xs_l =
                ((layer == 0) ? (xs + (size_t)t * 4096)
                              : (hb_in + (size_t)p_out * 16384)) + laneoff;
            const unsigned* hs_l = hb_l + (size_t)p_prev * 16384 + laneoff;

            f32x4 acc[4] = {{0.f,0.f,0.f,0.f},{0.f,0.f,0.f,0.f},
                            {0.f,0.f,0.f,0.f},{0.f,0.f,0.f,0.f}};
            if (layer == 0) step_mfma<4, false>(xs_l, hs_l, wfrag, lane, acc);
            else            step_mfma<16, true>(xs_l, hs_l, wfrag, lane, acc);

            // In-register finalize: reg g of acc[rg] = gate g of (fb, c0+rg*4+q).
#pragma unroll
            for (int rg = 0; rg < 4; ++rg) {
                float a[4];
#pragma unroll
                for (int g = 0; g < 4; ++g)
                    a[g] = bias[rg][g] + acc[rg][g];

                const float ig = sigmoid_(a[0]);
                const float fg = sigmoid_(a[1]);
                const float gg = tanh_(a[2]);
                const float og = sigmoid_(a[3]);
                c_reg[rg] = fg * c_reg[rg] + ig * gg;
                const float hv = og * tanh_(c_reg[rg]);

                // cols (q,q^1) pair via shfl_xor(16) -> dword; dwords (q=0,q=2)
                // pair via shfl_xor(32) -> u64; q==0 lane stores.
                const unsigned P0 = (unsigned)f2h(hv);
                const unsigned P1 = (unsigned)__shfl_xor((int)P0, 16, 64) & 0xFFFFu;
                const unsigned D  = P0 | (P1 << 16);
                const unsigned D2 = (unsigned)__shfl_xor((int)D, 32, 64);
                if (q == 0) {
                    storec_u64(&hb_l[(size_t)p_out * 16384 + hstore[rg]],
                               ((unsigned long long)D2 << 32) | D);
                }
            }
        }
        gbar(bar_slots, bid, tid, s + 1);
    }

    // ---- FC head. h2 = layer-2 h at t=511 (parity 1), fp16 kquad layout.
    const unsigned* h2u = hb + (size_t)2 * 32768 + 16384;
    const int fcb = tid & 63;
    if (bid < 64) {
        float part = 0.0f;
        const float* wrow = fcW1 + (size_t)bid * H_ + w * 128;
#pragma unroll 8
        for (int k = 0; k < 128; ++k) {
            const int kk = w * 128 + k;
            const unsigned dv =
                loadc_u32(h2u + (kk >> 2) * 128 + fcb * 2 + ((kk >> 1) & 1));
            const float val = h2f((unsigned short)((dv >> ((kk & 1) * 16)) & 0xFFFFu));
            part = fmaf(wrow[k], val, part);
        }
        redsc[w * 64 + fcb] = part;
        __syncthreads();
        if (tid < 64) {
            float acc2 = fcb1[bid] + redsc[tid] + redsc[64 + tid] +
                         redsc[128 + tid] + redsc[192 + tid];
            storec_f(&h1s[bid * B_ + tid], fmaxf(acc2, 0.0f));
        }
    }
    gbar(bar_slots, bid, tid, T_ + 3);
    if (bid == 0 && tid < 64) {
        float acc2 = fcb2[0];
#pragma unroll
        for (int c = 0; c < 64; ++c)
            acc2 = fmaf(fcW2[c], loadc_f(&h1s[c * B_ + tid]), acc2);
        out[tid] = fmaxf(acc2, 0.0f);
    }
}

// ---------------------------------------------------------------------------
extern "C" void kernel_launch(void* const* d_in, const int* in_sizes, int n_in,
                              void* d_out, int out_size, void* d_ws, size_t ws_size,
                              hipStream_t stream) {
    const float* in    = (const float*)d_in[0];
    const float* Wih0  = (const float*)d_in[1];
    const float* Whh0  = (const float*)d_in[2];
    const float* bih0  = (const float*)d_in[3];
    const float* bhh0  = (const float*)d_in[4];
    const float* Wih1  = (const float*)d_in[5];
    const float* Whh1  = (const float*)d_in[6];
    const float* bih1  = (const float*)d_in[7];
    const float* bhh1  = (const float*)d_in[8];
    const float* Wih2  = (const float*)d_in[9];
    const float* Whh2  = (const float*)d_in[10];
    const float* bih2  = (const float*)d_in[11];
    const float* bhh2  = (const float*)d_in[12];
    const float* fcW1  = (const float*)d_in[13];
    const float* fcb1  = (const float*)d_in[14];
    const float* fcW2  = (const float*)d_in[15];
    const float* fcb2  = (const float*)d_in[16];
    float* outp = (float*)d_out;

    unsigned* xs  = (unsigned*)d_ws;                   // [T][4096] dwords  8 MB
    unsigned* hbf = xs + (size_t)T_ * 4096;            // [3][2][16384]   384 KB
    float*    h1s = (float*)(hbf + (size_t)3 * 32768); // [64][64]         16 KB
    int*      bar = (int*)(h1s + 64 * 64);
    int*      bar_slots = bar;                         // NBLK*16 ints
    int*      bar_go    = bar + NBLK * 16;             // 1 int (unused)

    hipMemsetAsync(hbf, 0,
                   ((size_t)3 * 32768 + 64 * 64 + NBLK * 16 + 16) * sizeof(int),
                   stream);

    transpose_x<<<dim3(T_), dim3(256), 0, stream>>>(in, xs);

    void* args[] = {
        (void*)&xs, (void*)&hbf, (void*)&h1s, (void*)&outp,
        (void*)&bar_slots, (void*)&bar_go,
        (void*)&Wih0, (void*)&Whh0, (void*)&bih0, (void*)&bhh0,
        (void*)&Wih1, (void*)&Whh1, (void*)&bih1, (void*)&bhh1,
        (void*)&Wih2, (void*)&Whh2, (void*)&bih2, (void*)&bhh2,
        (void*)&fcW1, (void*)&fcb1, (void*)&fcW2, (void*)&fcb2};
    hipLaunchCooperativeKernel((void*)lstm_scan, dim3(NBLK), dim3(256), args, 0, stream);
}